// Round 5
// baseline (179.249 us; speedup 1.0000x reference)
//
#include <hip/hip_runtime.h>

typedef __bf16  bf16x8 __attribute__((ext_vector_type(8)));
typedef float   f32x4  __attribute__((ext_vector_type(4)));
typedef short   short8 __attribute__((ext_vector_type(8)));

static __device__ __forceinline__ unsigned short f2bf(float f) {
  union { float f; unsigned int u; } v; v.f = f;
  unsigned int u = v.u;
  u += 0x7fffu + ((u >> 16) & 1u);   // round-to-nearest-even
  return (unsigned short)(u >> 16);
}

// e2m1 decode: code = sign<<3 | e<<1 | m ; values {0,.5,1,1.5,2,3,4,6} * sign
static __device__ __forceinline__ float fp4_decode(int qc) {
  int e = (qc >> 1) & 3;
  float m = (float)(qc & 1);
  float mag = (e == 0) ? (0.5f * m)
                       : ((2.0f + m) * 0.5f * (float)(1 << (e - 1)));
  return (qc & 8) ? -mag : mag;
}

// Fused prep: blocks [0, nblkW/256) dequant W; rest convert x.
__global__ __launch_bounds__(256) void w4a16_prep(
    const int* __restrict__ wq, const float* __restrict__ wsc,
    short* __restrict__ wout, int nblkW,
    const float* __restrict__ x, short* __restrict__ xb, int n8) {
  const int nbW = nblkW >> 8;
  if ((int)blockIdx.x < nbW) {
    int idx = blockIdx.x * 256 + threadIdx.x;
    if (idx >= nblkW) return;
    float s = wsc[idx];
    const int4* qp = (const int4*)wq + (size_t)idx * 4;
    int4 q0 = qp[0], q1 = qp[1], q2 = qp[2], q3 = qp[3];
    short8 r0, r1;
    r0[0] = (short)f2bf(fp4_decode(q0.x) * s);
    r0[1] = (short)f2bf(fp4_decode(q0.y) * s);
    r0[2] = (short)f2bf(fp4_decode(q0.z) * s);
    r0[3] = (short)f2bf(fp4_decode(q0.w) * s);
    r0[4] = (short)f2bf(fp4_decode(q1.x) * s);
    r0[5] = (short)f2bf(fp4_decode(q1.y) * s);
    r0[6] = (short)f2bf(fp4_decode(q1.z) * s);
    r0[7] = (short)f2bf(fp4_decode(q1.w) * s);
    r1[0] = (short)f2bf(fp4_decode(q2.x) * s);
    r1[1] = (short)f2bf(fp4_decode(q2.y) * s);
    r1[2] = (short)f2bf(fp4_decode(q2.z) * s);
    r1[3] = (short)f2bf(fp4_decode(q2.w) * s);
    r1[4] = (short)f2bf(fp4_decode(q3.x) * s);
    r1[5] = (short)f2bf(fp4_decode(q3.y) * s);
    r1[6] = (short)f2bf(fp4_decode(q3.z) * s);
    r1[7] = (short)f2bf(fp4_decode(q3.w) * s);
    short8* op = (short8*)wout + (size_t)idx * 2;
    op[0] = r0;
    op[1] = r1;
  } else {
    int idx = (blockIdx.x - nbW) * 256 + threadIdx.x;
    if (idx >= n8) return;
    const float4* xp = (const float4*)x + (size_t)idx * 2;
    float4 a = xp[0], b = xp[1];
    short8 r;
    r[0] = (short)f2bf(a.x); r[1] = (short)f2bf(a.y);
    r[2] = (short)f2bf(a.z); r[3] = (short)f2bf(a.w);
    r[4] = (short)f2bf(b.x); r[5] = (short)f2bf(b.y);
    r[6] = (short)f2bf(b.z); r[7] = (short)f2bf(b.w);
    ((short8*)xb)[idx] = r;
  }
}

// ---------------------------------------------------------------------------
// C[M,N] = A[M,K] * B[N,K]^T, bf16 in, fp32 out.
// BM=128 x BN=256, BK=64, 8 waves (2x4), per-wave 64x64.
// A: global->register fragments (L1 serves x4 cross-wave reuse), double-
//    buffered one tile ahead (static indices via x2 unroll).
// B: LDS double-buffer (64KB), global_load_lds w/ T2 source-swizzle, 1-ahead.
// One barrier per tile; boundary = sched_barrier + vmcnt(8) (drains B(t+1)x4,
// keeps A(t+1)x8 in flight; VMEM completes in issue order) + s_barrier.
// ---------------------------------------------------------------------------
#define BM 128
#define BN 256
#define BK 64
#define BSZ (BN * BK)          // shorts per B buffer (16384 = 32KB)

__global__ __launch_bounds__(512, 2) void w4a16_gemm_areg(
    const short* __restrict__ A, const short* __restrict__ B,
    float* __restrict__ C, int M, int N, int K) {
  __shared__ __attribute__((aligned(16))) short Bs[2 * BSZ];  // 64KB

  const int tid  = threadIdx.x;
  const int lane = tid & 63;
  const int wid  = tid >> 6;      // 0..7
  const int wr   = wid >> 2;      // 0..1  (M)
  const int wc   = wid & 3;       // 0..3  (N)

  const int bm = blockIdx.y * BM;
  const int bn = blockIdx.x * BN;

  f32x4 acc[4][4] = {};           // [m-frag][n-frag]

  const int fr    = lane & 15;
  const int klane = lane >> 4;    // k-offset = klane*8 elements
  const int xv    = fr & 7;       // read-side swizzle XOR

  const size_t rowbytes = (size_t)K * 2;

  // ---- B staging addresses (loop-invariant; only kt varies)
  size_t boff[4];  int bldso[4];
#pragma unroll
  for (int r = 0; r < 4; ++r) {
    int u = r * 512 + tid;               // 0..2047
    int row = u >> 3, c = u & 7;
    int csrc = c ^ (row & 7);
    boff[r]  = (size_t)(bn + row) * rowbytes + (size_t)csrc * 16;
    bldso[r] = u * 16;
  }
  const char* Bg = (const char*)B;

#define STAGE_B(bufbase, koff2, r)                                              \
  __builtin_amdgcn_global_load_lds(                                             \
      (const __attribute__((address_space(1))) unsigned int*)(Bg + boff[r] + (koff2)), \
      (__attribute__((address_space(3))) unsigned int*)((char*)(bufbase) + bldso[r]),  \
      16, 0, 0)

  // ---- A fragment global pointers (per-lane, MFMA A-layout direct)
  const char* Apl[4];
#pragma unroll
  for (int mi = 0; mi < 4; ++mi) {
    int row = bm + wr * 64 + mi * 16 + fr;
    Apl[mi] = (const char*)A + (size_t)row * rowbytes + klane * 16;
  }

  // swizzled B fragment reads from LDS
  auto readB = [&](const short* Bb, int ni, int kk) -> bf16x8 {
    int row = wc * 64 + ni * 16 + fr;
    int c = kk * 4 + klane;
    return *(const bf16x8*)((const char*)Bb + (size_t)row * 128 + ((c ^ xv) << 4));
  };

  const int NT = K / BK;   // 64
  short* Bs0 = Bs;
  short* Bs1 = Bs + BSZ;

  bf16x8 bfr[4][2], afA[4][2], afB[4][2];

  // ---- prologue: stage B(0), load A(0) frags; confirm B(0), publish.
  STAGE_B(Bs0, 0, 0); STAGE_B(Bs0, 0, 1); STAGE_B(Bs0, 0, 2); STAGE_B(Bs0, 0, 3);
  __builtin_amdgcn_sched_barrier(0);
#pragma unroll
  for (int mi = 0; mi < 4; ++mi)
#pragma unroll
    for (int kk = 0; kk < 2; ++kk)
      afA[mi][kk] = *(const bf16x8*)(Apl[mi] + kk * 64);
  __builtin_amdgcn_sched_barrier(0);
  asm volatile("s_waitcnt vmcnt(8)");      // B(0) resident; A(0) in flight
  __builtin_amdgcn_s_barrier();

#define TILE_BODY(t_, CURB, NXTB, AFU, AFL)                                     \
  do {                                                                          \
    _Pragma("unroll") for (int ni = 0; ni < 4; ++ni)                            \
      _Pragma("unroll") for (int kk = 0; kk < 2; ++kk)                          \
        bfr[ni][kk] = readB((CURB), ni, kk);                                    \
    const bool pf_ = (t_) + 1 < NT;                                             \
    if (pf_) {                                                                  \
      const size_t ko_ = (size_t)((t_) + 1) * (BK * 2);                         \
      STAGE_B((NXTB), ko_, 0); STAGE_B((NXTB), ko_, 1);                         \
      STAGE_B((NXTB), ko_, 2); STAGE_B((NXTB), ko_, 3);                         \
    }                                                                           \
    __builtin_amdgcn_sched_barrier(0);  /* pin: B-stage issued before A-loads */\
    if (pf_) {                                                                  \
      _Pragma("unroll") for (int mi = 0; mi < 4; ++mi)                          \
        _Pragma("unroll") for (int kk = 0; kk < 2; ++kk)                        \
          AFL[mi][kk] = *(const bf16x8*)(Apl[mi] + ((t_) + 1) * 128 + kk * 64); \
    }                                                                           \
    __builtin_amdgcn_s_setprio(1);                                              \
    _Pragma("unroll") for (int mi = 0; mi < 4; ++mi)                            \
      _Pragma("unroll") for (int ni = 0; ni < 4; ++ni)                          \
        _Pragma("unroll") for (int kk = 0; kk < 2; ++kk)                        \
          acc[mi][ni] = __builtin_amdgcn_mfma_f32_16x16x32_bf16(                \
              AFU[mi][kk], bfr[ni][kk], acc[mi][ni], 0, 0, 0);                  \
    __builtin_amdgcn_s_setprio(0);                                              \
    if ((t_) < NT - 1) {                                                        \
      __builtin_amdgcn_sched_barrier(0);                                        \
      asm volatile("s_waitcnt vmcnt(8)");  /* drain B(t+1)x4; keep A(t+1)x8 */  \
      __builtin_amdgcn_s_barrier();                                             \
    }                                                                           \
  } while (0)

  for (int t = 0; t < NT; t += 2) {
    TILE_BODY(t,     Bs0, Bs1, afA, afB);
    TILE_BODY(t + 1, Bs1, Bs0, afB, afA);
  }

  // ---- epilogue: C/D map: col = lane&15, row = (lane>>4)*4 + reg
  const int cn = lane & 15;
  const int rb = (lane >> 4) * 4;
#pragma unroll
  for (int ai = 0; ai < 4; ++ai)
#pragma unroll
    for (int bj = 0; bj < 4; ++bj) {
      int m0 = bm + wr * 64 + ai * 16 + rb;
      int n0 = bn + wc * 64 + bj * 16 + cn;
#pragma unroll
      for (int r = 0; r < 4; ++r)
        C[(size_t)(m0 + r) * N + n0] = acc[ai][bj][r];
    }
}

extern "C" void kernel_launch(void* const* d_in, const int* in_sizes, int n_in,
                              void* d_out, int out_size, void* d_ws, size_t ws_size,
                              hipStream_t stream) {
  const float* x   = (const float*)d_in[0];
  const float* wsc = (const float*)d_in[1];
  const int*   wq  = (const int*)d_in[2];
  float* out = (float*)d_out;

  const int K = 4096;                 // in_features
  const int N = in_sizes[2] / K;      // out_features = 4096
  const int M = in_sizes[0] / K;      // batch*seq = 2048

  // workspace layout: W bf16 [N*K] then X bf16 [M*K]
  short* Wb = (short*)d_ws;
  short* Xb = Wb + (size_t)N * K;

  int nblkW = (N * K) / 16;           // 1048576
  int n8    = (M * K) / 8;            // 1048576
  int gridP = (nblkW >> 8) + ((n8 + 255) >> 8);
  w4a16_prep<<<gridP, 256, 0, stream>>>(wq, wsc, Wb, nblkW, x, Xb, n8);

  dim3 grid(N / BN, M / BM);
  w4a16_gemm_areg<<<grid, 512, 0, stream>>>(Xb, Wb, out, M, N, K);
}

// Round 6
// 101.343 us; speedup vs baseline: 1.7687x; 1.7687x over previous
//
#include <hip/hip_runtime.h>

typedef __bf16  bf16x8 __attribute__((ext_vector_type(8)));
typedef float   f32x4  __attribute__((ext_vector_type(4)));
typedef short   short8 __attribute__((ext_vector_type(8)));

static __device__ __forceinline__ unsigned short f2bf(float f) {
  union { float f; unsigned int u; } v; v.f = f;
  unsigned int u = v.u;
  u += 0x7fffu + ((u >> 16) & 1u);   // round-to-nearest-even
  return (unsigned short)(u >> 16);
}

// e2m1 decode: code = sign<<3 | e<<1 | m ; values {0,.5,1,1.5,2,3,4,6} * sign
static __device__ __forceinline__ float fp4_decode(int qc) {
  int e = (qc >> 1) & 3;
  float m = (float)(qc & 1);
  float mag = (e == 0) ? (0.5f * m)
                       : ((2.0f + m) * 0.5f * (float)(1 << (e - 1)));
  return (qc & 8) ? -mag : mag;
}

// Fused prep: blocks [0, nblkW/256) dequant W; rest convert x.
__global__ __launch_bounds__(256) void w4a16_prep(
    const int* __restrict__ wq, const float* __restrict__ wsc,
    short* __restrict__ wout, int nblkW,
    const float* __restrict__ x, short* __restrict__ xb, int n8) {
  const int nbW = nblkW >> 8;
  if ((int)blockIdx.x < nbW) {
    int idx = blockIdx.x * 256 + threadIdx.x;
    if (idx >= nblkW) return;
    float s = wsc[idx];
    const int4* qp = (const int4*)wq + (size_t)idx * 4;
    int4 q0 = qp[0], q1 = qp[1], q2 = qp[2], q3 = qp[3];
    short8 r0, r1;
    r0[0] = (short)f2bf(fp4_decode(q0.x) * s);
    r0[1] = (short)f2bf(fp4_decode(q0.y) * s);
    r0[2] = (short)f2bf(fp4_decode(q0.z) * s);
    r0[3] = (short)f2bf(fp4_decode(q0.w) * s);
    r0[4] = (short)f2bf(fp4_decode(q1.x) * s);
    r0[5] = (short)f2bf(fp4_decode(q1.y) * s);
    r0[6] = (short)f2bf(fp4_decode(q1.z) * s);
    r0[7] = (short)f2bf(fp4_decode(q1.w) * s);
    r1[0] = (short)f2bf(fp4_decode(q2.x) * s);
    r1[1] = (short)f2bf(fp4_decode(q2.y) * s);
    r1[2] = (short)f2bf(fp4_decode(q2.z) * s);
    r1[3] = (short)f2bf(fp4_decode(q2.w) * s);
    r1[4] = (short)f2bf(fp4_decode(q3.x) * s);
    r1[5] = (short)f2bf(fp4_decode(q3.y) * s);
    r1[6] = (short)f2bf(fp4_decode(q3.z) * s);
    r1[7] = (short)f2bf(fp4_decode(q3.w) * s);
    short8* op = (short8*)wout + (size_t)idx * 2;
    op[0] = r0;
    op[1] = r1;
  } else {
    int idx = (blockIdx.x - nbW) * 256 + threadIdx.x;
    if (idx >= n8) return;
    const float4* xp = (const float4*)x + (size_t)idx * 2;
    float4 a = xp[0], b = xp[1];
    short8 r;
    r[0] = (short)f2bf(a.x); r[1] = (short)f2bf(a.y);
    r[2] = (short)f2bf(a.z); r[3] = (short)f2bf(a.w);
    r[4] = (short)f2bf(b.x); r[5] = (short)f2bf(b.y);
    r[6] = (short)f2bf(b.z); r[7] = (short)f2bf(b.w);
    ((short8*)xb)[idx] = r;
  }
}

// ---------------------------------------------------------------------------
// C[M,N] = A[M,K] * B[N,K]^T, bf16 in, fp32 out.
// BM=BN=128, BK=32, 4 waves (2x2), per-wave 64x64. NBUF=3 -> 48KB LDS ->
// 3 blocks/CU: independent blocks overlap LDS and MFMA pipes (m114).
// One barrier per tile (R4-proven): {8 ds_read + 4 stage-issue -> 16 MFMA
// (compiler-counted lgkm) -> sched_barrier -> vmcnt(4) -> s_barrier}.
// Swizzle (rows are 64B = 4 chunks): chunk c XOR ((row>>1)&3) on stage-SOURCE
// and on READ -> 2-way bank aliasing (free) instead of 8-way.
// ---------------------------------------------------------------------------
#define BM 128
#define BN 128
#define BK 32
#define NBUF 3
#define ASZ (BM * BK)          // 4096 shorts = 8KB
#define BSZ (BN * BK)          // 4096 shorts = 8KB

__global__ __launch_bounds__(256, 3) void w4a16_gemm_occ(
    const short* __restrict__ A, const short* __restrict__ B,
    float* __restrict__ C, int M, int N, int K) {
  __shared__ __attribute__((aligned(16))) short As[NBUF * ASZ];  // 24KB
  __shared__ __attribute__((aligned(16))) short Bs[NBUF * BSZ];  // 24KB

  const int tid  = threadIdx.x;
  const int lane = tid & 63;
  const int wid  = tid >> 6;      // 0..3
  const int wr   = wid >> 1;      // 0..1  (M)
  const int wc   = wid & 1;       // 0..1  (N)

  const int bm = blockIdx.y * BM;
  const int bn = blockIdx.x * BN;

  f32x4 acc[4][4] = {};           // [m-frag][n-frag]

  const int fr    = lane & 15;
  const int klane = lane >> 4;          // k-offset = klane*8 elems = 16B chunk
  const int xk    = klane ^ ((fr >> 1) & 3);   // swizzled read chunk

  const size_t rowbytes = (size_t)K * 2;

  // ---- staging addresses (loop-invariant; only kt varies).
  // tile = 128 rows x 32 cols x 2B; row = 64B = 4 chunks of 16B.
  size_t aoff[2], boff[2];  int ldso[2];
#pragma unroll
  for (int r = 0; r < 2; ++r) {
    int u = r * 256 + tid;               // 0..511
    int row = u >> 2, c = u & 3;
    int csrc = c ^ ((row >> 1) & 3);
    aoff[r] = (size_t)(bm + row) * rowbytes + (size_t)csrc * 16;
    boff[r] = (size_t)(bn + row) * rowbytes + (size_t)csrc * 16;
    ldso[r] = u * 16;
  }
  const char* Ag = (const char*)A;
  const char* Bg = (const char*)B;

#define STAGE_A(bufbase, koff2, r)                                              \
  __builtin_amdgcn_global_load_lds(                                             \
      (const __attribute__((address_space(1))) unsigned int*)(Ag + aoff[r] + (koff2)), \
      (__attribute__((address_space(3))) unsigned int*)((char*)(bufbase) + ldso[r]),   \
      16, 0, 0)
#define STAGE_B(bufbase, koff2, r)                                              \
  __builtin_amdgcn_global_load_lds(                                             \
      (const __attribute__((address_space(1))) unsigned int*)(Bg + boff[r] + (koff2)), \
      (__attribute__((address_space(3))) unsigned int*)((char*)(bufbase) + ldso[r]),   \
      16, 0, 0)

  // swizzled fragment reads (row length 64B; chunk = xk)
  auto readA = [&](const short* Ab, int mi) -> bf16x8 {
    int row = wr * 64 + mi * 16 + fr;
    return *(const bf16x8*)((const char*)Ab + (size_t)row * 64 + (xk << 4));
  };
  auto readB = [&](const short* Bb, int ni) -> bf16x8 {
    int row = wc * 64 + ni * 16 + fr;
    return *(const bf16x8*)((const char*)Bb + (size_t)row * 64 + (xk << 4));
  };

  const int NT = K / BK;   // 128

  // ---- prologue: stage tiles 0 and 1; confirm tile 0 resident.
  {
    char* A0 = (char*)As;            char* B0 = (char*)Bs;
    char* A1 = (char*)(As + ASZ);    char* B1 = (char*)(Bs + BSZ);
    STAGE_A(A0, 0, 0); STAGE_A(A0, 0, 1);
    STAGE_B(B0, 0, 0); STAGE_B(B0, 0, 1);
    size_t k2 = (size_t)BK * 2;
    STAGE_A(A1, k2, 0); STAGE_A(A1, k2, 1);
    STAGE_B(B1, k2, 0); STAGE_B(B1, k2, 1);
  }
  asm volatile("s_waitcnt vmcnt(4)");      // tile 0 complete, tile 1 in flight
  __builtin_amdgcn_s_barrier();

  int cur = 0, nxt = 2;
  for (int t = 0; t < NT; ++t) {
    const short* Ab = As + cur * ASZ;
    const short* Bb = Bs + cur * BSZ;
    char* An = (char*)(As + nxt * ASZ);
    char* Bn = (char*)(Bs + nxt * BSZ);
    const size_t koff2 = (size_t)(t + 2) * (BK * 2);
    const bool pf = (t + 2) < NT;

    bf16x8 af[4], bf[4];
#pragma unroll
    for (int mi = 0; mi < 4; ++mi) af[mi] = readA(Ab, mi);
#pragma unroll
    for (int ni = 0; ni < 4; ++ni) bf[ni] = readB(Bb, ni);

    if (pf) {
      STAGE_A(An, koff2, 0); STAGE_A(An, koff2, 1);
      STAGE_B(Bn, koff2, 0); STAGE_B(Bn, koff2, 1);
    }

    __builtin_amdgcn_s_setprio(1);
#pragma unroll
    for (int mi = 0; mi < 4; ++mi)
#pragma unroll
      for (int ni = 0; ni < 4; ++ni)
        acc[mi][ni] = __builtin_amdgcn_mfma_f32_16x16x32_bf16(
            af[mi], bf[ni], acc[mi][ni], 0, 0, 0);
    __builtin_amdgcn_s_setprio(0);

    if (t < NT - 1) {
      __builtin_amdgcn_sched_barrier(0);
      if (pf) asm volatile("s_waitcnt vmcnt(4)");  // t+1 resident; t+2 in flight
      else    asm volatile("s_waitcnt vmcnt(0)");
    }
    __builtin_amdgcn_s_barrier();

    cur = (cur == NBUF - 1) ? 0 : cur + 1;
    nxt = (nxt == NBUF - 1) ? 0 : nxt + 1;
  }

  // ---- epilogue: C/D map: col = lane&15, row = (lane>>4)*4 + reg
  const int cn = lane & 15;
  const int rb = (lane >> 4) * 4;
#pragma unroll
  for (int ai = 0; ai < 4; ++ai)
#pragma unroll
    for (int bj = 0; bj < 4; ++bj) {
      int m0 = bm + wr * 64 + ai * 16 + rb;
      int n0 = bn + wc * 64 + bj * 16 + cn;
#pragma unroll
      for (int r = 0; r < 4; ++r)
        C[(size_t)(m0 + r) * N + n0] = acc[ai][bj][r];
    }
}

extern "C" void kernel_launch(void* const* d_in, const int* in_sizes, int n_in,
                              void* d_out, int out_size, void* d_ws, size_t ws_size,
                              hipStream_t stream) {
  const float* x   = (const float*)d_in[0];
  const float* wsc = (const float*)d_in[1];
  const int*   wq  = (const int*)d_in[2];
  float* out = (float*)d_out;

  const int K = 4096;                 // in_features
  const int N = in_sizes[2] / K;      // out_features = 4096
  const int M = in_sizes[0] / K;      // batch*seq = 2048

  // workspace layout: W bf16 [N*K] then X bf16 [M*K]
  short* Wb = (short*)d_ws;
  short* Xb = Wb + (size_t)N * K;

  int nblkW = (N * K) / 16;           // 1048576
  int n8    = (M * K) / 8;            // 1048576
  int gridP = (nblkW >> 8) + ((n8 + 255) >> 8);
  w4a16_prep<<<gridP, 256, 0, stream>>>(wq, wsc, Wb, nblkW, x, Xb, n8);

  dim3 grid(N / BN, M / BM);
  w4a16_gemm_occ<<<grid, 256, 0, stream>>>(Xb, Wb, out, M, N, K);
}